// Round 3
// baseline (31.347 us; speedup 1.0000x reference)
//
#include <hip/hip_runtime.h>
#include <hip/hip_bf16.h>

// EdgeConv: B=8, C=64, N=4096, K=16, O=64
// h[b,n,k,:] = relu(x_i @ (Wa-Wb) + x_j @ Wb + bias); out = max_k h
// K=128 augmented-row MFMA: A row e = [x_i | x_j_e], B = Wmod[128][64].

#define BB 8
#define CC 64
#define NN 4096
#define KK 16
#define OO 64

typedef __bf16 bf16x8 __attribute__((ext_vector_type(8)));
typedef float f32x4 __attribute__((ext_vector_type(4)));

union Frag { int4 i; bf16x8 v; };

static constexpr size_t XTB_ELEMS = (size_t)BB * NN * CC;   // 4 MB bf16
static constexpr size_t WFRAG_ELEMS = 4 * 4 * 64 * 8;       // 16 KB bf16
static constexpr int NXT = BB * (NN / 64);                  // 512 x-transpose blocks

// Fused prep: blocks [0,512) transpose+cast x -> xtb [B,N,C] bf16;
// block 512 builds Wmod=[[Wa-Wb],[Wb]] in MFMA B-fragment order.
__global__ __launch_bounds__(256) void prep(const float* __restrict__ x,
                                            const float* __restrict__ W,
                                            __hip_bfloat16* __restrict__ xtb,
                                            __hip_bfloat16* __restrict__ wfrag) {
    int t = threadIdx.x;
    if (blockIdx.x == NXT) {
        for (int idx = t; idx < (int)WFRAG_ELEMS; idx += 256) {
            int j = idx & 7, lane = (idx >> 3) & 63, ot = (idx >> 9) & 3, s = idx >> 11;
            int kdim = s * 32 + (lane >> 4) * 8 + j;
            int o = ot * 16 + (lane & 15);
            float v = (kdim < 64) ? (W[kdim * OO + o] - W[(kdim + 64) * OO + o])
                                  : W[kdim * OO + o];
            wfrag[idx] = __float2bfloat16(v);
        }
        return;
    }
    __shared__ float tile[64][65];
    int b = blockIdx.x >> 6;
    int n0 = (blockIdx.x & 63) << 6;
    const float* xb = x + (size_t)b * CC * NN;
    #pragma unroll
    for (int it = 0; it < 16; ++it) {
        int idx = it * 256 + t;
        int c = idx >> 6, nn = idx & 63;
        tile[c][nn] = xb[c * NN + n0 + nn];                 // coalesced along n
    }
    __syncthreads();
    __hip_bfloat16* xo = xtb + ((size_t)b * NN + n0) * CC;
    #pragma unroll
    for (int it = 0; it < 16; ++it) {
        int idx = it * 256 + t;
        int nl = idx >> 6, c = idx & 63;
        xo[nl * CC + c] = __float2bfloat16(tile[c][nl]);    // coalesced along c
    }
}

// Main: one wave per 8 nodes. W-fragments + block's x_i rows staged in LDS
// (kills the 4x-redundant wf global traffic and x_i loads in the hot loop).
__global__ __launch_bounds__(256, 3) void edgeconv_main(
    const int* __restrict__ ei, const float* __restrict__ bias,
    const __hip_bfloat16* __restrict__ xtb, const __hip_bfloat16* __restrict__ wfrag,
    float* __restrict__ out) {
    __shared__ int4 wfl[16][64];      // 16 KB: [s*4+ot][lane]
    __shared__ int4 xil[32][8];       // 4 KB: block's 32 node rows (8 int4 each)
    __shared__ float otile[64][33];   // 8.4 KB

    int t = threadIdx.x;
    int w = t >> 6, l = t & 63;
    int b = blockIdx.x >> 7;            // 128 32-node tiles per batch
    int n0 = (blockIdx.x & 127) << 5;

    const int4* wf4 = (const int4*)wfrag;
    #pragma unroll
    for (int i = 0; i < 4; ++i) {       // stage wfrag: 1024 int4, coalesced
        int idx = i * 256 + t;
        wfl[idx >> 6][idx & 63] = wf4[idx];
    }
    const int4* xt4 = (const int4*)(xtb + (size_t)b * NN * CC);
    xil[t >> 3][t & 7] = xt4[(n0 + (t >> 3)) * 8 + (t & 7)];  // stage 32 x_i rows

    float bv[4];
    #pragma unroll
    for (int ot = 0; ot < 4; ++ot) bv[ot] = bias[ot * 16 + (l & 15)];

    const int* srcp = ei + (size_t)b * NN * KK;   // ei[0][b]
    int lg = l >> 4;   // K-chunk group 0..3
    int le = l & 15;   // edge index / output col
    int nbase = n0 + w * 8;

    int vidx[8];
    #pragma unroll
    for (int i = 0; i < 8; ++i) vidx[i] = srcp[(nbase + i) * KK + le];

    __syncthreads();

    // W fragments from LDS into regs (ds_read_b128, 16x)
    Frag wf[4][4];
    #pragma unroll
    for (int s = 0; s < 4; ++s)
        #pragma unroll
        for (int ot = 0; ot < 4; ++ot)
            wf[s][ot].i = wfl[s * 4 + ot][l];

    // 2-deep x_j gather pipeline, all indices compile-time under full unroll
    Frag aj[2][2];
    aj[0][0].i = xt4[vidx[0] * 8 + lg];
    aj[0][1].i = xt4[vidx[0] * 8 + 4 + lg];

    #pragma unroll
    for (int i = 0; i < 8; ++i) {
        if (i < 7) {
            int v = vidx[i + 1];
            aj[(i + 1) & 1][0].i = xt4[v * 8 + lg];
            aj[(i + 1) & 1][1].i = xt4[v * 8 + 4 + lg];
        }
        int nl = w * 8 + i;
        Frag ai0, ai1;
        ai0.i = xil[nl][lg];        // LDS broadcast (16 lanes same addr)
        ai1.i = xil[nl][4 + lg];

        f32x4 acc[4];
        #pragma unroll
        for (int ot = 0; ot < 4; ++ot) acc[ot] = f32x4{bv[ot], bv[ot], bv[ot], bv[ot]};

        #pragma unroll
        for (int ot = 0; ot < 4; ++ot) {
            acc[ot] = __builtin_amdgcn_mfma_f32_16x16x32_bf16(ai0.v, wf[0][ot].v, acc[ot], 0, 0, 0);
            acc[ot] = __builtin_amdgcn_mfma_f32_16x16x32_bf16(ai1.v, wf[1][ot].v, acc[ot], 0, 0, 0);
            acc[ot] = __builtin_amdgcn_mfma_f32_16x16x32_bf16(aj[i & 1][0].v, wf[2][ot].v, acc[ot], 0, 0, 0);
            acc[ot] = __builtin_amdgcn_mfma_f32_16x16x32_bf16(aj[i & 1][1].v, wf[3][ot].v, acc[ot], 0, 0, 0);
        }

        // D layout: col = lane&15 (=o), row = (lane>>4)*4 + reg (=edge). Max over 16 edges.
        #pragma unroll
        for (int ot = 0; ot < 4; ++ot) {
            float r = fmaxf(fmaxf(acc[ot][0], acc[ot][1]), fmaxf(acc[ot][2], acc[ot][3]));
            r = fmaxf(r, __shfl_xor(r, 16));
            r = fmaxf(r, __shfl_xor(r, 32));
            r = fmaxf(r, 0.0f);            // relu commutes with max
            if (l < 16) otile[ot * 16 + l][nl] = r;
        }
    }
    __syncthreads();
    // Coalesced write of the 64x32 tile to out[b][o][n]
    float* ob = out + (size_t)b * OO * NN;
    #pragma unroll
    for (int it = 0; it < 8; ++it) {
        int idx = it * 256 + t;
        int o = idx >> 5, nn = idx & 31;
        ob[(size_t)o * NN + n0 + nn] = otile[o][nn];
    }
}

extern "C" void kernel_launch(void* const* d_in, const int* in_sizes, int n_in,
                              void* d_out, int out_size, void* d_ws, size_t ws_size,
                              hipStream_t stream) {
    const float* x    = (const float*)d_in[0];   // [B,C,N,1] f32
    const int*   ei   = (const int*)d_in[1];     // [2,B,N,K] i32
    const float* W    = (const float*)d_in[2];   // [128,64] f32
    const float* bias = (const float*)d_in[3];   // [64] f32
    float* out = (float*)d_out;                  // [B,O,N,1] f32

    __hip_bfloat16* xtb   = (__hip_bfloat16*)d_ws;           // 4 MB
    __hip_bfloat16* wfrag = xtb + XTB_ELEMS;                 // +16 KB

    hipLaunchKernelGGL(prep, dim3(NXT + 1), dim3(256), 0, stream, x, W, xtb, wfrag);
    hipLaunchKernelGGL(edgeconv_main, dim3(BB * (NN / 32)), dim3(256), 0, stream,
                       ei, bias, xtb, wfrag, out);
}